// Round 1
// baseline (2642.504 us; speedup 1.0000x reference)
//
#include <hip/hip_runtime.h>
#include <math.h>

// Problem dims
#define B_SZ 32
#define S_SZ 512
#define C_SZ 512
#define E_SZ 256
#define H_SZ 8
#define D_SZ 32
#define L_SZ 4
#define N_TOK (B_SZ * S_SZ)   // 16384
#define HID 768               // 3*E

__device__ __forceinline__ float gelu_f(float x) {
    // exact gelu: 0.5*x*(1+erf(x/sqrt(2)))
    return 0.5f * x * (1.0f + erff(x * 0.70710678118654752f));
}

// ---------------------------------------------------------------------------
// GEMM: C[M,F] = A[M,K] @ W[F,K]^T + bias (+bias2), activation ACT
// ACT: 0 = none, 1 = gelu(exact), 2 = relu
// M%64==0, F%64==0, K%32==0 (all shapes in this net satisfy this)
// ---------------------------------------------------------------------------
template<int ACT>
__global__ __launch_bounds__(256)
void gemm_bt_kernel(const float* __restrict__ A, const float* __restrict__ W,
                    const float* __restrict__ bias, const float* __restrict__ bias2,
                    float* __restrict__ C, int M, int K, int F)
{
    constexpr int BM = 64, BN = 64, BK = 32;
    __shared__ float As[BK][BM + 4];  // row stride 68 floats = 272B (16B aligned)
    __shared__ float Bs[BK][BN + 4];
    const int tid = threadIdx.x;
    const int tx = tid & 15, ty = tid >> 4;
    const int bm = blockIdx.x * BM, bn = blockIdx.y * BN;
    const int f4 = tid & 7;       // which k-float4 chunk (0..7)
    const int r0 = tid >> 3;      // tile row 0..31 (and +32)
    float acc[4][4] = {};

    for (int k0 = 0; k0 < K; k0 += BK) {
        #pragma unroll
        for (int rr = 0; rr < 2; ++rr) {
            const int r = r0 + rr * 32;
            const float4 av = *(const float4*)(A + (size_t)(bm + r) * K + k0 + f4 * 4);
            const float4 wv = *(const float4*)(W + (size_t)(bn + r) * K + k0 + f4 * 4);
            As[f4 * 4 + 0][r] = av.x; As[f4 * 4 + 1][r] = av.y;
            As[f4 * 4 + 2][r] = av.z; As[f4 * 4 + 3][r] = av.w;
            Bs[f4 * 4 + 0][r] = wv.x; Bs[f4 * 4 + 1][r] = wv.y;
            Bs[f4 * 4 + 2][r] = wv.z; Bs[f4 * 4 + 3][r] = wv.w;
        }
        __syncthreads();
        #pragma unroll
        for (int kk = 0; kk < BK; ++kk) {
            const float4 a4 = *(const float4*)&As[kk][ty * 4];
            const float4 b4 = *(const float4*)&Bs[kk][tx * 4];
            const float ar[4] = {a4.x, a4.y, a4.z, a4.w};
            const float br[4] = {b4.x, b4.y, b4.z, b4.w};
            #pragma unroll
            for (int i = 0; i < 4; ++i)
                #pragma unroll
                for (int j = 0; j < 4; ++j)
                    acc[i][j] = fmaf(ar[i], br[j], acc[i][j]);
        }
        __syncthreads();
    }

    #pragma unroll
    for (int i = 0; i < 4; ++i) {
        const int row = bm + ty * 4 + i;
        float vv[4];
        #pragma unroll
        for (int j = 0; j < 4; ++j) {
            const int col = bn + tx * 4 + j;
            float t = acc[i][j];
            if (bias)  t += bias[col];
            if (bias2) t += bias2[col];
            if (ACT == 1) t = gelu_f(t);
            if (ACT == 2) t = fmaxf(t, 0.0f);
            vv[j] = t;
        }
        float4 o; o.x = vv[0]; o.y = vv[1]; o.z = vv[2]; o.w = vv[3];
        *(float4*)(C + (size_t)row * F + bn + tx * 4) = o;
    }
}

// ---------------------------------------------------------------------------
// Fused attention: one block per (b,h). K,V staged in LDS; each thread owns
// 2 query rows with single-pass online softmax.
// q,k,v,out layout: [B,S,E] with head h at columns h*32..h*32+31.
// ---------------------------------------------------------------------------
__global__ __launch_bounds__(256)
void attn_kernel(const float* __restrict__ q, const float* __restrict__ k,
                 const float* __restrict__ v, float* __restrict__ out)
{
    __shared__ float Ks[S_SZ][36];  // pad to 36: conflict-free staging, aligned rows
    __shared__ float Vs[S_SZ][36];
    const int bh = blockIdx.x;           // 0..255
    const int b = bh >> 3, h = bh & 7;
    const size_t base = (size_t)b * S_SZ * E_SZ + (size_t)h * D_SZ;
    const int tid = threadIdx.x;

    // stage K,V (512 rows x 32 floats each)
    #pragma unroll
    for (int it = 0; it < 16; ++it) {
        const int idx = tid + it * 256;      // 0..4095
        const int s = idx >> 3, d4 = idx & 7;
        const float4 kv = *(const float4*)(k + base + (size_t)s * E_SZ + d4 * 4);
        const float4 vv = *(const float4*)(v + base + (size_t)s * E_SZ + d4 * 4);
        *(float4*)&Ks[s][d4 * 4] = kv;
        *(float4*)&Vs[s][d4 * 4] = vv;
    }

    // load this thread's two q rows
    float qa[32], qb[32];
    #pragma unroll
    for (int d4 = 0; d4 < 8; ++d4) {
        const float4 t0 = *(const float4*)(q + base + (size_t)tid * E_SZ + d4 * 4);
        const float4 t1 = *(const float4*)(q + base + (size_t)(tid + 256) * E_SZ + d4 * 4);
        qa[d4 * 4 + 0] = t0.x; qa[d4 * 4 + 1] = t0.y; qa[d4 * 4 + 2] = t0.z; qa[d4 * 4 + 3] = t0.w;
        qb[d4 * 4 + 0] = t1.x; qb[d4 * 4 + 1] = t1.y; qb[d4 * 4 + 2] = t1.z; qb[d4 * 4 + 3] = t1.w;
    }
    __syncthreads();

    const float scale = 0.17677669529663689f;  // 1/sqrt(32)
    float m0 = -INFINITY, m1 = -INFINITY, l0 = 0.f, l1 = 0.f;
    float acc0[32] = {}, acc1[32] = {};

    for (int s = 0; s < S_SZ; ++s) {
        float kr[32];
        #pragma unroll
        for (int d4 = 0; d4 < 8; ++d4) {
            const float4 t = *(const float4*)&Ks[s][d4 * 4];
            kr[d4 * 4 + 0] = t.x; kr[d4 * 4 + 1] = t.y; kr[d4 * 4 + 2] = t.z; kr[d4 * 4 + 3] = t.w;
        }
        float d0 = 0.f, d1 = 0.f;
        #pragma unroll
        for (int d = 0; d < 32; ++d) {
            d0 = fmaf(qa[d], kr[d], d0);
            d1 = fmaf(qb[d], kr[d], d1);
        }
        d0 *= scale; d1 *= scale;

        if (d0 > m0) {
            const float c = __expf(m0 - d0);   // exp(-inf)=0 handles first iter
            l0 *= c;
            #pragma unroll
            for (int d = 0; d < 32; ++d) acc0[d] *= c;
            m0 = d0;
        }
        if (d1 > m1) {
            const float c = __expf(m1 - d1);
            l1 *= c;
            #pragma unroll
            for (int d = 0; d < 32; ++d) acc1[d] *= c;
            m1 = d1;
        }
        const float p0 = __expf(d0 - m0);
        const float p1 = __expf(d1 - m1);
        l0 += p0; l1 += p1;

        #pragma unroll
        for (int d4 = 0; d4 < 8; ++d4) {
            const float4 t = *(const float4*)&Vs[s][d4 * 4];
            acc0[d4 * 4 + 0] = fmaf(p0, t.x, acc0[d4 * 4 + 0]);
            acc0[d4 * 4 + 1] = fmaf(p0, t.y, acc0[d4 * 4 + 1]);
            acc0[d4 * 4 + 2] = fmaf(p0, t.z, acc0[d4 * 4 + 2]);
            acc0[d4 * 4 + 3] = fmaf(p0, t.w, acc0[d4 * 4 + 3]);
            acc1[d4 * 4 + 0] = fmaf(p1, t.x, acc1[d4 * 4 + 0]);
            acc1[d4 * 4 + 1] = fmaf(p1, t.y, acc1[d4 * 4 + 1]);
            acc1[d4 * 4 + 2] = fmaf(p1, t.z, acc1[d4 * 4 + 2]);
            acc1[d4 * 4 + 3] = fmaf(p1, t.w, acc1[d4 * 4 + 3]);
        }
    }

    const float i0 = 1.0f / l0, i1 = 1.0f / l1;
    #pragma unroll
    for (int d4 = 0; d4 < 8; ++d4) {
        float4 o0, o1;
        o0.x = acc0[d4 * 4 + 0] * i0; o0.y = acc0[d4 * 4 + 1] * i0;
        o0.z = acc0[d4 * 4 + 2] * i0; o0.w = acc0[d4 * 4 + 3] * i0;
        o1.x = acc1[d4 * 4 + 0] * i1; o1.y = acc1[d4 * 4 + 1] * i1;
        o1.z = acc1[d4 * 4 + 2] * i1; o1.w = acc1[d4 * 4 + 3] * i1;
        *(float4*)(out + base + (size_t)tid * E_SZ + d4 * 4) = o0;
        *(float4*)(out + base + (size_t)(tid + 256) * E_SZ + d4 * 4) = o1;
    }
}

// ---------------------------------------------------------------------------
// x = LN(x + resid) * w + b   (resid may be null -> plain LN). In-place on x.
// One wave (64 lanes) per row of 256; block = 4 rows.
// ---------------------------------------------------------------------------
__global__ __launch_bounds__(256)
void add_ln_kernel(float* __restrict__ x, const float* __restrict__ resid,
                   const float* __restrict__ w, const float* __restrict__ b)
{
    const int lane = threadIdx.x & 63;
    const int wv = threadIdx.x >> 6;
    const size_t row = (size_t)blockIdx.x * 4 + wv;
    float4 val = *(const float4*)(x + row * E_SZ + lane * 4);
    if (resid) {
        const float4 r = *(const float4*)(resid + row * E_SZ + lane * 4);
        val.x += r.x; val.y += r.y; val.z += r.z; val.w += r.w;
    }
    float s  = val.x + val.y + val.z + val.w;
    float ss = val.x * val.x + val.y * val.y + val.z * val.z + val.w * val.w;
    #pragma unroll
    for (int off = 1; off < 64; off <<= 1) {
        s  += __shfl_xor(s, off, 64);
        ss += __shfl_xor(ss, off, 64);
    }
    const float mu  = s * (1.0f / 256.0f);
    const float var = ss * (1.0f / 256.0f) - mu * mu;
    const float rs  = rsqrtf(var + 1e-5f);
    const float4 wv4 = *(const float4*)(w + lane * 4);
    const float4 bv4 = *(const float4*)(b + lane * 4);
    float4 o;
    o.x = (val.x - mu) * rs * wv4.x + bv4.x;
    o.y = (val.y - mu) * rs * wv4.y + bv4.y;
    o.z = (val.z - mu) * rs * wv4.z + bv4.z;
    o.w = (val.w - mu) * rs * wv4.w + bv4.w;
    *(float4*)(x + row * E_SZ + lane * 4) = o;
}

// ---------------------------------------------------------------------------
static void launch_gemm(int act, const float* A, const float* W, const float* bias,
                        const float* bias2, float* C, int M, int K, int F,
                        hipStream_t stream)
{
    dim3 grid(M / 64, F / 64), block(256);
    if (act == 0)
        gemm_bt_kernel<0><<<grid, block, 0, stream>>>(A, W, bias, bias2, C, M, K, F);
    else if (act == 1)
        gemm_bt_kernel<1><<<grid, block, 0, stream>>>(A, W, bias, bias2, C, M, K, F);
    else
        gemm_bt_kernel<2><<<grid, block, 0, stream>>>(A, W, bias, bias2, C, M, K, F);
}

extern "C" void kernel_launch(void* const* d_in, const int* in_sizes, int n_in,
                              void* d_out, int out_size, void* d_ws, size_t ws_size,
                              hipStream_t stream)
{
    const float* cnn   = (const float*)d_in[0];
    const float* cnn_w = (const float*)d_in[1];
    const float* cnn_b = (const float*)d_in[2];
    const float* tok   = (const float*)d_in[3];   // [2,E]; row 0 used
    const float* Wq    = (const float*)d_in[4];
    const float* bq    = (const float*)d_in[5];
    const float* Wk    = (const float*)d_in[6];
    const float* bk    = (const float*)d_in[7];
    const float* Wv    = (const float*)d_in[8];
    const float* bv    = (const float*)d_in[9];
    const float* Wo    = (const float*)d_in[10];
    const float* bo    = (const float*)d_in[11];
    const float* ln1w  = (const float*)d_in[12];
    const float* ln1b  = (const float*)d_in[13];
    const float* ln2w  = (const float*)d_in[14];
    const float* ln2b  = (const float*)d_in[15];
    const float* mw1   = (const float*)d_in[16];
    const float* mb1   = (const float*)d_in[17];
    const float* mw2   = (const float*)d_in[18];
    const float* mb2   = (const float*)d_in[19];
    const float* lnfw  = (const float*)d_in[20];
    const float* lnfb  = (const float*)d_in[21];
    const float* ow1   = (const float*)d_in[22];
    const float* ob1   = (const float*)d_in[23];
    const float* ow2   = (const float*)d_in[24];
    const float* ob2   = (const float*)d_in[25];

    const int M = N_TOK;                      // 16384
    const size_t NE = (size_t)N_TOK * E_SZ;   // 4,194,304 floats

    float* ws  = (float*)d_ws;
    float* x   = ws;            // [N,E]
    float* qb_ = ws + NE;       // [N,E]
    float* kb_ = ws + 2 * NE;   // [N,E]
    float* vb_ = ws + 3 * NE;   // [N,E]
    float* ab_ = ws + 4 * NE;   // [N,E]  attention result / mlp_out
    float* tmp = qb_;           // [N,768] aliases q/k/v region (3*NE floats)

    // x = cnn_features @ cnn_w^T + cnn_b + tok_emb[0]
    launch_gemm(0, cnn, cnn_w, cnn_b, tok, x, M, C_SZ, E_SZ, stream);

    for (int i = 0; i < L_SZ; ++i) {
        const float* Wq_i = Wq + (size_t)i * E_SZ * E_SZ;
        const float* Wk_i = Wk + (size_t)i * E_SZ * E_SZ;
        const float* Wv_i = Wv + (size_t)i * E_SZ * E_SZ;
        const float* Wo_i = Wo + (size_t)i * E_SZ * E_SZ;
        const float* bq_i = bq + (size_t)i * E_SZ;
        const float* bk_i = bk + (size_t)i * E_SZ;
        const float* bv_i = bv + (size_t)i * E_SZ;
        const float* bo_i = bo + (size_t)i * E_SZ;

        launch_gemm(0, x, Wq_i, bq_i, nullptr, qb_, M, E_SZ, E_SZ, stream);
        launch_gemm(0, x, Wk_i, bk_i, nullptr, kb_, M, E_SZ, E_SZ, stream);
        launch_gemm(0, x, Wv_i, bv_i, nullptr, vb_, M, E_SZ, E_SZ, stream);

        attn_kernel<<<dim3(B_SZ * H_SZ), dim3(256), 0, stream>>>(qb_, kb_, vb_, ab_);

        // attn_out = attended @ Wo^T + bo  -> kb_ (free now)
        launch_gemm(0, ab_, Wo_i, bo_i, nullptr, kb_, M, E_SZ, E_SZ, stream);
        // x = LN(x + attn_out)
        add_ln_kernel<<<dim3(M / 4), dim3(256), 0, stream>>>(
            x, kb_, ln1w + (size_t)i * E_SZ, ln1b + (size_t)i * E_SZ);

        // h = gelu(x @ mlp_w1^T + mlp_b1)  -> tmp [N,768]
        launch_gemm(1, x, mw1 + (size_t)i * HID * E_SZ, mb1 + (size_t)i * HID,
                    nullptr, tmp, M, E_SZ, HID, stream);
        // mlp_out = h @ mlp_w2^T + mlp_b2 -> ab_
        launch_gemm(0, tmp, mw2 + (size_t)i * E_SZ * HID, mb2 + (size_t)i * E_SZ,
                    nullptr, ab_, M, HID, E_SZ, stream);
        // x = LN(x + mlp_out)
        add_ln_kernel<<<dim3(M / 4), dim3(256), 0, stream>>>(
            x, ab_, ln2w + (size_t)i * E_SZ, ln2b + (size_t)i * E_SZ);
    }

    // x = LN(x)
    add_ln_kernel<<<dim3(M / 4), dim3(256), 0, stream>>>(x, nullptr, lnfw, lnfb);

    // h = gelu(x @ out_w1^T + out_b1)  [N,512] -> tmp
    launch_gemm(1, x, ow1, ob1, nullptr, tmp, M, E_SZ, 2 * E_SZ, stream);
    // out = relu(h @ out_w2^T + out_b2) [N,512] -> d_out
    launch_gemm(2, tmp, ow2, ob2, nullptr, (float*)d_out, M, 2 * E_SZ, C_SZ, stream);
}

// Round 2
// 1628.581 us; speedup vs baseline: 1.6226x; 1.6226x over previous
//
#include <hip/hip_runtime.h>
#include <math.h>

// Problem dims
#define B_SZ 32
#define S_SZ 512
#define C_SZ 512
#define E_SZ 256
#define H_SZ 8
#define D_SZ 32
#define L_SZ 4
#define N_TOK (B_SZ * S_SZ)   // 16384
#define HID 768               // 3*E

typedef __attribute__((ext_vector_type(8))) short bf16x8;
typedef __attribute__((ext_vector_type(4))) float f32x4_t;

__device__ __forceinline__ float gelu_f(float x) {
    return 0.5f * x * (1.0f + erff(x * 0.70710678118654752f));
}

__device__ __forceinline__ ushort f2bf(float f) {
    // round-to-nearest-even f32 -> bf16 (inputs are finite)
    uint u = __float_as_uint(f);
    return (ushort)((u + 0x7FFFu + ((u >> 16) & 1u)) >> 16);
}
__device__ __forceinline__ uint pack2(float a, float b) {
    return (uint)f2bf(a) | ((uint)f2bf(b) << 16);
}
__device__ __forceinline__ float bf2f(ushort u) {
    return __uint_as_float(((uint)u) << 16);
}
__device__ __forceinline__ void unpack8(uint4 u, float* f) {
    f[0] = __uint_as_float((u.x & 0xFFFFu) << 16); f[1] = __uint_as_float(u.x & 0xFFFF0000u);
    f[2] = __uint_as_float((u.y & 0xFFFFu) << 16); f[3] = __uint_as_float(u.y & 0xFFFF0000u);
    f[4] = __uint_as_float((u.z & 0xFFFFu) << 16); f[5] = __uint_as_float(u.z & 0xFFFF0000u);
    f[6] = __uint_as_float((u.w & 0xFFFFu) << 16); f[7] = __uint_as_float(u.w & 0xFFFF0000u);
}

// ---------------------------------------------------------------------------
// fp32 -> bf16 conversion (n % 2048 == 0, grid = n/2048)
// ---------------------------------------------------------------------------
__global__ __launch_bounds__(256)
void cvt_kernel(const float* __restrict__ src, ushort* __restrict__ dst)
{
    const int i = (blockIdx.x * 256 + threadIdx.x) * 8;
    const float4 a = *(const float4*)(src + i);
    const float4 b = *(const float4*)(src + i + 4);
    uint4 o;
    o.x = pack2(a.x, a.y); o.y = pack2(a.z, a.w);
    o.z = pack2(b.x, b.y); o.w = pack2(b.z, b.w);
    *(uint4*)(dst + i) = o;
}

// ---------------------------------------------------------------------------
// bf16 MFMA GEMM: C[M,F] = A[M,K](bf16) @ W[F,K](bf16)^T + bias (+bias2), ACT
// Tile 128x64, BK=32, 4 waves (2x2), wave tile 64x32 of 16x16x32 fragments.
// LDS row stride 40 bf16 (80B): <=2-way bank conflicts (free).
// M%128==0, F%64==0, K%32==0.
// ---------------------------------------------------------------------------
template<int ACT, bool OF, bool OB>
__global__ __launch_bounds__(256)
void gemm_bf16_kernel(const ushort* __restrict__ A, const ushort* __restrict__ W,
                      const float* __restrict__ bias, const float* __restrict__ bias2,
                      float* __restrict__ Cf, ushort* __restrict__ Cb,
                      int M, int K, int F)
{
    constexpr int LDT = 40;
    __shared__ __align__(16) ushort As[128 * LDT];
    __shared__ __align__(16) ushort Bs[64 * LDT];
    const int tid = threadIdx.x;
    const int bm = blockIdx.x * 128, bn = blockIdx.y * 64;
    const int ar = tid >> 2, aks = tid & 3;   // staging: row, 8-elem k-segment

    uint4 pa0, pa1, pb;
    {
        const size_t k0 = 0;
        pa0 = *(const uint4*)(A + (size_t)(bm + ar) * K + k0 + aks * 8);
        pa1 = *(const uint4*)(A + (size_t)(bm + ar + 64) * K + k0 + aks * 8);
        pb  = *(const uint4*)(W + (size_t)(bn + ar) * K + k0 + aks * 8);
    }

    const int lane = tid & 63, w = tid >> 6;
    const int wm = w >> 1, wn = w & 1;
    const int fr = lane & 15, fk = lane >> 4;
    f32x4_t acc[4][2] = {};

    for (int k0 = 0;;) {
        __syncthreads();
        *(uint4*)&As[ar * LDT + aks * 8] = pa0;
        *(uint4*)&As[(ar + 64) * LDT + aks * 8] = pa1;
        *(uint4*)&Bs[ar * LDT + aks * 8] = pb;
        __syncthreads();
        k0 += 32;
        if (k0 < K) {
            pa0 = *(const uint4*)(A + (size_t)(bm + ar) * K + k0 + aks * 8);
            pa1 = *(const uint4*)(A + (size_t)(bm + ar + 64) * K + k0 + aks * 8);
            pb  = *(const uint4*)(W + (size_t)(bn + ar) * K + k0 + aks * 8);
        }
        bf16x8 af[4], bw[2];
        #pragma unroll
        for (int i = 0; i < 4; ++i)
            af[i] = *(const bf16x8*)&As[(wm * 64 + i * 16 + fr) * LDT + fk * 8];
        #pragma unroll
        for (int j = 0; j < 2; ++j)
            bw[j] = *(const bf16x8*)&Bs[(wn * 32 + j * 16 + fr) * LDT + fk * 8];
        #pragma unroll
        for (int i = 0; i < 4; ++i)
            #pragma unroll
            for (int j = 0; j < 2; ++j)
                acc[i][j] = __builtin_amdgcn_mfma_f32_16x16x32_bf16(af[i], bw[j], acc[i][j], 0, 0, 0);
        if (k0 >= K) break;
    }

    // Epilogue. C/D layout (m89-verified): col = lane&15, row = (lane>>4)*4 + reg.
    #pragma unroll
    for (int j = 0; j < 2; ++j) {
        const int col = bn + wn * 32 + j * 16 + fr;
        float bb = bias[col];
        if (bias2) bb += bias2[col];
        #pragma unroll
        for (int i = 0; i < 4; ++i) {
            #pragma unroll
            for (int r = 0; r < 4; ++r) {
                const int row = bm + wm * 64 + i * 16 + fk * 4 + r;
                float t = acc[i][j][r] + bb;
                if (ACT == 1) t = gelu_f(t);
                if (ACT == 2) t = fmaxf(t, 0.0f);
                if (OF) Cf[(size_t)row * F + col] = t;
                if (OB) Cb[(size_t)row * F + col] = f2bf(t);
            }
        }
    }
}

// ---------------------------------------------------------------------------
// Attention v2: grid (B*H, S/256). 256 threads, 1 q-row/thread, online softmax.
// K/V (bf16 in global) staged per 128-row chunk into LDS as fp32 (36.9 KB ->
// 2 blocks/CU, 8 waves/CU). q pre-scaled by 1/sqrt(D). Output bf16.
// ---------------------------------------------------------------------------
__global__ __launch_bounds__(256)
void attn_v2(const ushort* __restrict__ q, const ushort* __restrict__ k,
             const ushort* __restrict__ v, ushort* __restrict__ out)
{
    __shared__ __align__(16) float Ks[128][36];
    __shared__ __align__(16) float Vs[128][36];
    const int bh = blockIdx.x;               // 0..255
    const int qc = blockIdx.y;               // 0..1
    const int b = bh >> 3, h = bh & 7;
    const size_t base = (size_t)b * S_SZ * E_SZ + (size_t)h * D_SZ;
    const int tid = threadIdx.x;
    const int srow = tid >> 2, sks = tid & 3;   // staging row (0..63), k-seg

    // load + pre-scale this thread's q row
    float qr[32];
    {
        const ushort* qp = q + base + (size_t)(qc * 256 + tid) * E_SZ;
        const float scale = 0.17677669529663689f;
        #pragma unroll
        for (int t = 0; t < 4; ++t) {
            float f[8];
            unpack8(*(const uint4*)(qp + t * 8), f);
            #pragma unroll
            for (int j = 0; j < 8; ++j) qr[t * 8 + j] = f[j] * scale;
        }
    }

    uint4 pk0, pk1, pv0, pv1;
    {
        const size_t r0 = (size_t)srow * E_SZ + sks * 8;
        pk0 = *(const uint4*)(k + base + r0);
        pk1 = *(const uint4*)(k + base + r0 + (size_t)64 * E_SZ);
        pv0 = *(const uint4*)(v + base + r0);
        pv1 = *(const uint4*)(v + base + r0 + (size_t)64 * E_SZ);
    }

    float m = -INFINITY, l = 0.f;
    float acc[32] = {};

    for (int c = 0; c < 4; ++c) {
        __syncthreads();
        {
            float f[8];
            unpack8(pk0, f);
            *(float4*)&Ks[srow][sks * 8]     = make_float4(f[0], f[1], f[2], f[3]);
            *(float4*)&Ks[srow][sks * 8 + 4] = make_float4(f[4], f[5], f[6], f[7]);
            unpack8(pk1, f);
            *(float4*)&Ks[srow + 64][sks * 8]     = make_float4(f[0], f[1], f[2], f[3]);
            *(float4*)&Ks[srow + 64][sks * 8 + 4] = make_float4(f[4], f[5], f[6], f[7]);
            unpack8(pv0, f);
            *(float4*)&Vs[srow][sks * 8]     = make_float4(f[0], f[1], f[2], f[3]);
            *(float4*)&Vs[srow][sks * 8 + 4] = make_float4(f[4], f[5], f[6], f[7]);
            unpack8(pv1, f);
            *(float4*)&Vs[srow + 64][sks * 8]     = make_float4(f[0], f[1], f[2], f[3]);
            *(float4*)&Vs[srow + 64][sks * 8 + 4] = make_float4(f[4], f[5], f[6], f[7]);
        }
        __syncthreads();
        if (c < 3) {
            const size_t r0 = (size_t)((c + 1) * 128 + srow) * E_SZ + sks * 8;
            pk0 = *(const uint4*)(k + base + r0);
            pk1 = *(const uint4*)(k + base + r0 + (size_t)64 * E_SZ);
            pv0 = *(const uint4*)(v + base + r0);
            pv1 = *(const uint4*)(v + base + r0 + (size_t)64 * E_SZ);
        }

        for (int s = 0; s < 128; ++s) {
            float d = 0.f;
            #pragma unroll
            for (int t4 = 0; t4 < 8; ++t4) {
                const float4 kk = *(const float4*)&Ks[s][t4 * 4];
                d = fmaf(qr[t4 * 4 + 0], kk.x, d);
                d = fmaf(qr[t4 * 4 + 1], kk.y, d);
                d = fmaf(qr[t4 * 4 + 2], kk.z, d);
                d = fmaf(qr[t4 * 4 + 3], kk.w, d);
            }
            if (d > m) {
                const float cr = __expf(m - d);   // exp(-inf)=0 on first hit
                l *= cr;
                #pragma unroll
                for (int t = 0; t < 32; ++t) acc[t] *= cr;
                m = d;
            }
            const float p = __expf(d - m);
            l += p;
            #pragma unroll
            for (int t4 = 0; t4 < 8; ++t4) {
                const float4 vv = *(const float4*)&Vs[s][t4 * 4];
                acc[t4 * 4 + 0] = fmaf(p, vv.x, acc[t4 * 4 + 0]);
                acc[t4 * 4 + 1] = fmaf(p, vv.y, acc[t4 * 4 + 1]);
                acc[t4 * 4 + 2] = fmaf(p, vv.z, acc[t4 * 4 + 2]);
                acc[t4 * 4 + 3] = fmaf(p, vv.w, acc[t4 * 4 + 3]);
            }
        }
    }

    const float inv = 1.0f / l;
    ushort* op = out + base + (size_t)(qc * 256 + tid) * E_SZ;
    #pragma unroll
    for (int t = 0; t < 4; ++t) {
        uint4 o;
        o.x = pack2(acc[t * 8 + 0] * inv, acc[t * 8 + 1] * inv);
        o.y = pack2(acc[t * 8 + 2] * inv, acc[t * 8 + 3] * inv);
        o.z = pack2(acc[t * 8 + 4] * inv, acc[t * 8 + 5] * inv);
        o.w = pack2(acc[t * 8 + 6] * inv, acc[t * 8 + 7] * inv);
        *(uint4*)(op + t * 8) = o;
    }
}

// ---------------------------------------------------------------------------
// x = LN(x + resid) in fp32 (in-place on x) + bf16 copy to xb.
// One wave per row of 256; block = 4 rows.
// ---------------------------------------------------------------------------
__global__ __launch_bounds__(256)
void add_ln2_kernel(float* __restrict__ x, const float* __restrict__ resid,
                    const float* __restrict__ w, const float* __restrict__ b,
                    ushort* __restrict__ xb)
{
    const int lane = threadIdx.x & 63;
    const int wv = threadIdx.x >> 6;
    const size_t row = (size_t)blockIdx.x * 4 + wv;
    float4 val = *(const float4*)(x + row * E_SZ + lane * 4);
    if (resid) {
        const float4 r = *(const float4*)(resid + row * E_SZ + lane * 4);
        val.x += r.x; val.y += r.y; val.z += r.z; val.w += r.w;
    }
    float s  = val.x + val.y + val.z + val.w;
    float ss = val.x * val.x + val.y * val.y + val.z * val.z + val.w * val.w;
    #pragma unroll
    for (int off = 1; off < 64; off <<= 1) {
        s  += __shfl_xor(s, off, 64);
        ss += __shfl_xor(ss, off, 64);
    }
    const float mu  = s * (1.0f / 256.0f);
    const float var = ss * (1.0f / 256.0f) - mu * mu;
    const float rs  = rsqrtf(var + 1e-5f);
    const float4 wv4 = *(const float4*)(w + lane * 4);
    const float4 bv4 = *(const float4*)(b + lane * 4);
    float4 o;
    o.x = (val.x - mu) * rs * wv4.x + bv4.x;
    o.y = (val.y - mu) * rs * wv4.y + bv4.y;
    o.z = (val.z - mu) * rs * wv4.z + bv4.z;
    o.w = (val.w - mu) * rs * wv4.w + bv4.w;
    *(float4*)(x + row * E_SZ + lane * 4) = o;
    ushort4 ob;
    ob.x = f2bf(o.x); ob.y = f2bf(o.y); ob.z = f2bf(o.z); ob.w = f2bf(o.w);
    *(ushort4*)(xb + row * E_SZ + lane * 4) = ob;
}

// ---------------------------------------------------------------------------
extern "C" void kernel_launch(void* const* d_in, const int* in_sizes, int n_in,
                              void* d_out, int out_size, void* d_ws, size_t ws_size,
                              hipStream_t stream)
{
    const float* cnn   = (const float*)d_in[0];
    const float* cnn_w = (const float*)d_in[1];
    const float* cnn_b = (const float*)d_in[2];
    const float* tok   = (const float*)d_in[3];
    const float* Wq    = (const float*)d_in[4];
    const float* bq    = (const float*)d_in[5];
    const float* Wk    = (const float*)d_in[6];
    const float* bk    = (const float*)d_in[7];
    const float* Wv    = (const float*)d_in[8];
    const float* bv    = (const float*)d_in[9];
    const float* Wo    = (const float*)d_in[10];
    const float* bo    = (const float*)d_in[11];
    const float* ln1w  = (const float*)d_in[12];
    const float* ln1b  = (const float*)d_in[13];
    const float* ln2w  = (const float*)d_in[14];
    const float* ln2b  = (const float*)d_in[15];
    const float* mw1   = (const float*)d_in[16];
    const float* mb1   = (const float*)d_in[17];
    const float* mw2   = (const float*)d_in[18];
    const float* mb2   = (const float*)d_in[19];
    const float* lnfw  = (const float*)d_in[20];
    const float* lnfb  = (const float*)d_in[21];
    const float* ow1   = (const float*)d_in[22];
    const float* ob1   = (const float*)d_in[23];
    const float* ow2   = (const float*)d_in[24];
    const float* ob2   = (const float*)d_in[25];

    const int M = N_TOK;
    char* ws = (char*)d_ws;

    // Workspace layout (bytes); total 81.8 MB
    float*  x    = (float*)(ws + 0);                        // [N,E] fp32, 16 MB
    ushort* xb   = (ushort*)(ws + 16777216);                // [N,E] bf16, 8 MB
    ushort* qb_  = (ushort*)(ws + 25165824);                // [N,E] bf16
    ushort* kb_  = (ushort*)(ws + 33554432);                // [N,E] bf16
    ushort* vb_  = (ushort*)(ws + 41943040);                // [N,E] bf16
    float*  resid= (float*)(ws + 25165824);                 // [N,E] fp32 (aliases q/k after attn)
    ushort* cnnb = (ushort*)(ws + 25165824);                // [N,C] bf16 (dead before qkv)
    ushort* ab_  = (ushort*)(ws + 50331648);                // [N,E] bf16 attn out
    ushort* hb_  = (ushort*)(ws + 50331648);                // [N,768] bf16 (after ab dead)
    ushort* wbuf = (ushort*)(ws + 75497472);                // converted weights, 6.3 MB

    ushort* cnn_wb = wbuf;
    ushort* Wqb    = wbuf + 131072;
    ushort* Wkb    = wbuf + 393216;
    ushort* Wvb    = wbuf + 655360;
    ushort* Wob    = wbuf + 917504;
    ushort* mw1b   = wbuf + 1179648;
    ushort* mw2b   = wbuf + 1966080;
    ushort* ow1b   = wbuf + 2752512;
    ushort* ow2b   = wbuf + 2883584;

    // Weight + input conversions (all sizes % 2048 == 0)
    cvt_kernel<<<dim3(8388608 / 2048), dim3(256), 0, stream>>>(cnn, cnnb);
    cvt_kernel<<<dim3(131072 / 2048), dim3(256), 0, stream>>>(cnn_w, cnn_wb);
    cvt_kernel<<<dim3(262144 / 2048), dim3(256), 0, stream>>>(Wq, Wqb);
    cvt_kernel<<<dim3(262144 / 2048), dim3(256), 0, stream>>>(Wk, Wkb);
    cvt_kernel<<<dim3(262144 / 2048), dim3(256), 0, stream>>>(Wv, Wvb);
    cvt_kernel<<<dim3(262144 / 2048), dim3(256), 0, stream>>>(Wo, Wob);
    cvt_kernel<<<dim3(786432 / 2048), dim3(256), 0, stream>>>(mw1, mw1b);
    cvt_kernel<<<dim3(786432 / 2048), dim3(256), 0, stream>>>(mw2, mw2b);
    cvt_kernel<<<dim3(131072 / 2048), dim3(256), 0, stream>>>(ow1, ow1b);
    cvt_kernel<<<dim3(262144 / 2048), dim3(256), 0, stream>>>(ow2, ow2b);

    // x = cnn @ cnn_w^T + cnn_b + tok[0]  -> x fp32 + xb bf16
    gemm_bf16_kernel<0, true, true><<<dim3(M / 128, E_SZ / 64), dim3(256), 0, stream>>>(
        cnnb, cnn_wb, cnn_b, tok, x, xb, M, C_SZ, E_SZ);

    for (int i = 0; i < L_SZ; ++i) {
        const ushort* Wq_i = Wqb + (size_t)i * E_SZ * E_SZ;
        const ushort* Wk_i = Wkb + (size_t)i * E_SZ * E_SZ;
        const ushort* Wv_i = Wvb + (size_t)i * E_SZ * E_SZ;
        const ushort* Wo_i = Wob + (size_t)i * E_SZ * E_SZ;

        gemm_bf16_kernel<0, false, true><<<dim3(M / 128, E_SZ / 64), dim3(256), 0, stream>>>(
            xb, Wq_i, bq + (size_t)i * E_SZ, nullptr, nullptr, qb_, M, E_SZ, E_SZ);
        gemm_bf16_kernel<0, false, true><<<dim3(M / 128, E_SZ / 64), dim3(256), 0, stream>>>(
            xb, Wk_i, bk + (size_t)i * E_SZ, nullptr, nullptr, kb_, M, E_SZ, E_SZ);
        gemm_bf16_kernel<0, false, true><<<dim3(M / 128, E_SZ / 64), dim3(256), 0, stream>>>(
            xb, Wv_i, bv + (size_t)i * E_SZ, nullptr, nullptr, vb_, M, E_SZ, E_SZ);

        attn_v2<<<dim3(B_SZ * H_SZ, S_SZ / 256), dim3(256), 0, stream>>>(qb_, kb_, vb_, ab_);

        // attn_out = ab @ Wo^T + bo -> resid fp32 (overwrites dead q/k)
        gemm_bf16_kernel<0, true, false><<<dim3(M / 128, E_SZ / 64), dim3(256), 0, stream>>>(
            ab_, Wo_i, bo + (size_t)i * E_SZ, nullptr, resid, nullptr, M, E_SZ, E_SZ);
        add_ln2_kernel<<<dim3(M / 4), dim3(256), 0, stream>>>(
            x, resid, ln1w + (size_t)i * E_SZ, ln1b + (size_t)i * E_SZ, xb);

        gemm_bf16_kernel<1, false, true><<<dim3(M / 128, HID / 64), dim3(256), 0, stream>>>(
            xb, mw1b + (size_t)i * HID * E_SZ, mb1 + (size_t)i * HID, nullptr,
            nullptr, hb_, M, E_SZ, HID);
        gemm_bf16_kernel<0, true, false><<<dim3(M / 128, E_SZ / 64), dim3(256), 0, stream>>>(
            hb_, mw2b + (size_t)i * E_SZ * HID, mb2 + (size_t)i * E_SZ, nullptr,
            resid, nullptr, M, HID, E_SZ);
        add_ln2_kernel<<<dim3(M / 4), dim3(256), 0, stream>>>(
            x, resid, ln2w + (size_t)i * E_SZ, ln2b + (size_t)i * E_SZ, xb);
    }

    // final LN -> xb
    add_ln2_kernel<<<dim3(M / 4), dim3(256), 0, stream>>>(x, nullptr, lnfw, lnfb, xb);

    // h = gelu(xb @ ow1^T + ob1) -> hb_ [N,512] bf16
    gemm_bf16_kernel<1, false, true><<<dim3(M / 128, (2 * E_SZ) / 64), dim3(256), 0, stream>>>(
        xb, ow1b, ob1, nullptr, nullptr, hb_, M, E_SZ, 2 * E_SZ);
    // out = relu(hb @ ow2^T + ob2) -> d_out fp32 [N,512]
    gemm_bf16_kernel<2, true, false><<<dim3(M / 128, C_SZ / 64), dim3(256), 0, stream>>>(
        hb_, ow2b, ob2, nullptr, (float*)d_out, nullptr, M, 2 * E_SZ, C_SZ);
}

// Round 4
// 592.791 us; speedup vs baseline: 4.4577x; 2.7473x over previous
//
#include <hip/hip_runtime.h>
#include <math.h>

// Problem dims
#define B_SZ 32
#define S_SZ 512
#define C_SZ 512
#define E_SZ 256
#define H_SZ 8
#define D_SZ 32
#define L_SZ 4
#define N_TOK (B_SZ * S_SZ)   // 16384
#define HID 768               // 3*E
#define MB (1048576)

typedef __attribute__((ext_vector_type(8))) short bf16x8;
typedef __attribute__((ext_vector_type(4))) float f32x4_t;

__device__ __forceinline__ float gelu_f(float x) {
    return 0.5f * x * (1.0f + erff(x * 0.70710678118654752f));
}

__device__ __forceinline__ ushort f2bf(float f) {
    uint u = __float_as_uint(f);
    return (ushort)((u + 0x7FFFu + ((u >> 16) & 1u)) >> 16);
}
__device__ __forceinline__ uint pack2(float a, float b) {
    return (uint)f2bf(a) | ((uint)f2bf(b) << 16);
}
__device__ __forceinline__ void unpack8(uint4 u, float* f) {
    f[0] = __uint_as_float((u.x & 0xFFFFu) << 16); f[1] = __uint_as_float(u.x & 0xFFFF0000u);
    f[2] = __uint_as_float((u.y & 0xFFFFu) << 16); f[3] = __uint_as_float(u.y & 0xFFFF0000u);
    f[4] = __uint_as_float((u.z & 0xFFFFu) << 16); f[5] = __uint_as_float(u.z & 0xFFFF0000u);
    f[6] = __uint_as_float((u.w & 0xFFFFu) << 16); f[7] = __uint_as_float(u.w & 0xFFFF0000u);
}

// ---------------------------------------------------------------------------
// fp32 -> bf16 conversion (n % 2048 == 0, grid = n/2048)
// ---------------------------------------------------------------------------
__global__ __launch_bounds__(256)
void cvt_kernel(const float* __restrict__ src, ushort* __restrict__ dst)
{
    const int i = (blockIdx.x * 256 + threadIdx.x) * 8;
    const float4 a = *(const float4*)(src + i);
    const float4 b = *(const float4*)(src + i + 4);
    uint4 o;
    o.x = pack2(a.x, a.y); o.y = pack2(a.z, a.w);
    o.z = pack2(b.x, b.y); o.w = pack2(b.z, b.w);
    *(uint4*)(dst + i) = o;
}

// concat per-layer q/k/v biases -> bqkv[L][768]; grid 12 x 256
__global__ __launch_bounds__(256)
void bqkv_kernel(const float* __restrict__ bq, const float* __restrict__ bk,
                 const float* __restrict__ bv, float* __restrict__ dst)
{
    const int idx = blockIdx.x * 256 + threadIdx.x;   // 0..3071
    const int layer = idx / 768, j = idx % 768;
    float v = (j < 256) ? bq[layer * 256 + j]
            : (j < 512) ? bk[layer * 256 + j - 256]
                        : bv[layer * 256 + j - 512];
    dst[layer * 768 + j] = v;
}

// ---------------------------------------------------------------------------
// bf16 MFMA GEMM: C[M,F] = A[M,K](bf16) @ W[F,K](bf16)^T + bias (+bias2), ACT
// Tile 128x64, BK=32, 4 waves (2x2). EPI=0: normal (OF->Cf fp32, OB->Cb bf16
// row-major F). EPI=1: fused QKV split: cols 0..511 -> Cb[row*512+col] (q|k),
// cols 512..767 (=v) -> Cb2 transposed [b][h][32][512].
// ---------------------------------------------------------------------------
template<int ACT, int EPI, bool OF, bool OB>
__global__ __launch_bounds__(256)
void gemm_bf16_kernel(const ushort* __restrict__ A, const ushort* __restrict__ W,
                      const float* __restrict__ bias, const float* __restrict__ bias2,
                      float* __restrict__ Cf, ushort* __restrict__ Cb,
                      ushort* __restrict__ Cb2, int M, int K, int F)
{
    constexpr int LDT = 40;
    __shared__ __align__(16) ushort As[128 * LDT];
    __shared__ __align__(16) ushort Bs[64 * LDT];
    const int tid = threadIdx.x;
    const int bm = blockIdx.x * 128, bn = blockIdx.y * 64;
    const int ar = tid >> 2, aks = tid & 3;

    uint4 pa0, pa1, pb;
    {
        pa0 = *(const uint4*)(A + (size_t)(bm + ar) * K + aks * 8);
        pa1 = *(const uint4*)(A + (size_t)(bm + ar + 64) * K + aks * 8);
        pb  = *(const uint4*)(W + (size_t)(bn + ar) * K + aks * 8);
    }

    const int lane = tid & 63, w = tid >> 6;
    const int wm = w >> 1, wn = w & 1;
    const int fr = lane & 15, fk = lane >> 4;
    f32x4_t acc[4][2] = {};

    for (int k0 = 0;;) {
        __syncthreads();
        *(uint4*)&As[ar * LDT + aks * 8] = pa0;
        *(uint4*)&As[(ar + 64) * LDT + aks * 8] = pa1;
        *(uint4*)&Bs[ar * LDT + aks * 8] = pb;
        __syncthreads();
        k0 += 32;
        if (k0 < K) {
            pa0 = *(const uint4*)(A + (size_t)(bm + ar) * K + k0 + aks * 8);
            pa1 = *(const uint4*)(A + (size_t)(bm + ar + 64) * K + k0 + aks * 8);
            pb  = *(const uint4*)(W + (size_t)(bn + ar) * K + k0 + aks * 8);
        }
        bf16x8 af[4], bw[2];
        #pragma unroll
        for (int i = 0; i < 4; ++i)
            af[i] = *(const bf16x8*)&As[(wm * 64 + i * 16 + fr) * LDT + fk * 8];
        #pragma unroll
        for (int j = 0; j < 2; ++j)
            bw[j] = *(const bf16x8*)&Bs[(wn * 32 + j * 16 + fr) * LDT + fk * 8];
        #pragma unroll
        for (int i = 0; i < 4; ++i)
            #pragma unroll
            for (int j = 0; j < 2; ++j)
                acc[i][j] = __builtin_amdgcn_mfma_f32_16x16x32_bf16(af[i], bw[j], acc[i][j], 0, 0, 0);
        if (k0 >= K) break;
    }

    // C/D layout: col = lane&15, row = (lane>>4)*4 + reg.
    #pragma unroll
    for (int j = 0; j < 2; ++j) {
        const int col = bn + wn * 32 + j * 16 + fr;
        float bb = bias[col];
        if (bias2) bb += bias2[col];
        #pragma unroll
        for (int i = 0; i < 4; ++i) {
            #pragma unroll
            for (int r = 0; r < 4; ++r) {
                const int row = bm + wm * 64 + i * 16 + fk * 4 + r;
                float t = acc[i][j][r] + bb;
                if (ACT == 1) t = gelu_f(t);
                if (ACT == 2) t = fmaxf(t, 0.0f);
                if (EPI == 1) {
                    const int b2 = row >> 9, s2 = row & 511;
                    if (col < 512) {
                        Cb[(size_t)row * 512 + col] = f2bf(t);
                    } else {
                        const int cc = col - 512;
                        Cb2[(size_t)(((b2 << 3) + (cc >> 5)) << 14) + ((cc & 31) << 9) + s2] = f2bf(t);
                    }
                } else {
                    if (OF) Cf[(size_t)row * F + col] = t;
                    if (OB) Cb[(size_t)row * F + col] = f2bf(t);
                }
            }
        }
    }
}

// ---------------------------------------------------------------------------
// MFMA flash attention. Grid (B*H, S/64). Block 256 = 4 waves; wave owns 16 q.
// qk: [N][512] bf16 (q cols 0..255, k cols 256..511, head h at h*32).
// vt: [b][h][32][512] bf16 (V transposed, written by the QKV GEMM).
// out: [N][256] bf16.
// Swapped QK^T (S^T = K.Q^T) + permuted K rows so that the softmax'd P frags
// are already in B-operand layout for the PV mfma (zero shuffles).
// ---------------------------------------------------------------------------
__global__ __launch_bounds__(256)
void attn_v3(const ushort* __restrict__ qk, const ushort* __restrict__ vt,
             ushort* __restrict__ out)
{
    __shared__ __align__(16) ushort Ks[128 * 40];
    __shared__ __align__(16) ushort Vs[32 * 168];
    const int bh = blockIdx.x, qc = blockIdx.y;
    const int b = bh >> 3, h = bh & 7;
    const int tid = threadIdx.x;
    const int w = tid >> 6, lane = tid & 63;
    const int g = lane >> 4, c = lane & 15;
    const size_t qrow = (size_t)b * 512 + qc * 64 + w * 16;

    // load + pre-scale this wave's Q fragment: lane holds Q[q=c][d=g*8..g*8+7]
    bf16x8 qf;
    {
        const uint4 qv = *(const uint4*)(qk + (qrow + c) * 512 + h * 32 + g * 8);
        float f[8]; unpack8(qv, f);
        const float scale = 0.17677669529663689f;
        union { uint u[4]; bf16x8 v; } qq;
        #pragma unroll
        for (int j = 0; j < 4; ++j) qq.u[j] = pack2(f[2*j] * scale, f[2*j+1] * scale);
        qf = qq.v;
    }

    float m = -INFINITY, l = 0.f;
    f32x4_t o0 = {0.f, 0.f, 0.f, 0.f}, o1 = {0.f, 0.f, 0.f, 0.f};
    const f32x4_t zz = {0.f, 0.f, 0.f, 0.f};

    for (int kt = 0; kt < 4; ++kt) {
        __syncthreads();
        // stage K tile (128 keys x 32 d), rows permuted within each 32-block
        #pragma unroll
        for (int i = 0; i < 2; ++i) {
            const int idx = tid + i * 256;
            const int kr = idx >> 2, seg = idx & 3;
            const uint4 kv = *(const uint4*)(qk + ((size_t)b * 512 + kt * 128 + kr) * 512
                                             + 256 + h * 32 + seg * 8);
            const int p = (((kr >> 2) & 1) << 4) | (((kr >> 3) & 3) << 2) | (kr & 3);
            const int pos = (kr & ~31) | p;
            *(uint4*)&Ks[pos * 40 + seg * 8] = kv;
        }
        // stage Vt tile (32 d x 128 keys), natural key order: 512 uint4 loads
        #pragma unroll
        for (int i = 0; i < 2; ++i) {
            const int idx = tid + i * 256;
            const int dr = idx >> 4, seg = idx & 15;
            const uint4 vv = *(const uint4*)(vt + (size_t)bh * 16384 + dr * 512
                                             + kt * 128 + seg * 8);
            *(uint4*)&Vs[dr * 168 + seg * 8] = vv;
        }
        __syncthreads();

        // S^T frags: 8 x mfma(K, Q)
        f32x4_t s[8];
        #pragma unroll
        for (int kf = 0; kf < 8; ++kf) {
            const bf16x8 kfrag = *(const bf16x8*)&Ks[(kf * 16 + c) * 40 + g * 8];
            s[kf] = __builtin_amdgcn_mfma_f32_16x16x32_bf16(kfrag, qf, zz, 0, 0, 0);
        }

        // online softmax (each lane holds 32 keys of its q=c; reduce over g)
        float mt = s[0][0];
        #pragma unroll
        for (int kf = 0; kf < 8; ++kf)
            #pragma unroll
            for (int r = 0; r < 4; ++r) mt = fmaxf(mt, s[kf][r]);
        mt = fmaxf(mt, __shfl_xor(mt, 16));
        mt = fmaxf(mt, __shfl_xor(mt, 32));
        const float mn = fmaxf(m, mt);
        const float corr = __expf(m - mn);   // exp(-inf)=0 on first tile
        m = mn;
        float lt = 0.f;
        #pragma unroll
        for (int kf = 0; kf < 8; ++kf)
            #pragma unroll
            for (int r = 0; r < 4; ++r) {
                const float p = __expf(s[kf][r] - mn);
                s[kf][r] = p; lt += p;
            }
        lt += __shfl_xor(lt, 16);
        lt += __shfl_xor(lt, 32);
        l = l * corr + lt;
        #pragma unroll
        for (int r = 0; r < 4; ++r) { o0[r] *= corr; o1[r] *= corr; }

        // PV: P frags are lane-local (key permutation); O^T = V^T . P^T
        #pragma unroll
        for (int t = 0; t < 4; ++t) {
            union { uint u[4]; bf16x8 v; } pf;
            pf.u[0] = pack2(s[2*t][0],   s[2*t][1]);
            pf.u[1] = pack2(s[2*t][2],   s[2*t][3]);
            pf.u[2] = pack2(s[2*t+1][0], s[2*t+1][1]);
            pf.u[3] = pack2(s[2*t+1][2], s[2*t+1][3]);
            const bf16x8 va0 = *(const bf16x8*)&Vs[(0 * 16 + c) * 168 + t * 32 + g * 8];
            const bf16x8 va1 = *(const bf16x8*)&Vs[(1 * 16 + c) * 168 + t * 32 + g * 8];
            o0 = __builtin_amdgcn_mfma_f32_16x16x32_bf16(va0, pf.v, o0, 0, 0, 0);
            o1 = __builtin_amdgcn_mfma_f32_16x16x32_bf16(va1, pf.v, o1, 0, 0, 0);
        }
    }

    // epilogue: O^T[d][q]: lane holds q=c, d = df*16 + g*4 + r
    const float inv = 1.0f / l;
    const size_t obase = (qrow + c) * 256 + h * 32;
    #pragma unroll
    for (int r = 0; r < 4; ++r) {
        out[obase + g * 4 + r]      = f2bf(o0[r] * inv);
        out[obase + 16 + g * 4 + r] = f2bf(o1[r] * inv);
    }
}

// ---------------------------------------------------------------------------
// x = LN(x + resid) in fp32 (in-place on x) + bf16 copy to xb.
// ---------------------------------------------------------------------------
__global__ __launch_bounds__(256)
void add_ln2_kernel(float* __restrict__ x, const float* __restrict__ resid,
                    const float* __restrict__ w, const float* __restrict__ b,
                    ushort* __restrict__ xb)
{
    const int lane = threadIdx.x & 63;
    const int wv = threadIdx.x >> 6;
    const size_t row = (size_t)blockIdx.x * 4 + wv;
    float4 val = *(const float4*)(x + row * E_SZ + lane * 4);
    if (resid) {
        const float4 r = *(const float4*)(resid + row * E_SZ + lane * 4);
        val.x += r.x; val.y += r.y; val.z += r.z; val.w += r.w;
    }
    float s  = val.x + val.y + val.z + val.w;
    float ss = val.x * val.x + val.y * val.y + val.z * val.z + val.w * val.w;
    #pragma unroll
    for (int off = 1; off < 64; off <<= 1) {
        s  += __shfl_xor(s, off, 64);
        ss += __shfl_xor(ss, off, 64);
    }
    const float mu  = s * (1.0f / 256.0f);
    const float var = ss * (1.0f / 256.0f) - mu * mu;
    const float rs  = rsqrtf(var + 1e-5f);
    const float4 wv4 = *(const float4*)(w + lane * 4);
    const float4 bv4 = *(const float4*)(b + lane * 4);
    float4 o;
    o.x = (val.x - mu) * rs * wv4.x + bv4.x;
    o.y = (val.y - mu) * rs * wv4.y + bv4.y;
    o.z = (val.z - mu) * rs * wv4.z + bv4.z;
    o.w = (val.w - mu) * rs * wv4.w + bv4.w;
    *(float4*)(x + row * E_SZ + lane * 4) = o;
    ushort4 ob;
    ob.x = f2bf(o.x); ob.y = f2bf(o.y); ob.z = f2bf(o.z); ob.w = f2bf(o.w);
    *(ushort4*)(xb + row * E_SZ + lane * 4) = ob;
}

// ---------------------------------------------------------------------------
extern "C" void kernel_launch(void* const* d_in, const int* in_sizes, int n_in,
                              void* d_out, int out_size, void* d_ws, size_t ws_size,
                              hipStream_t stream)
{
    const float* cnn   = (const float*)d_in[0];
    const float* cnn_w = (const float*)d_in[1];
    const float* cnn_b = (const float*)d_in[2];
    const float* tok   = (const float*)d_in[3];
    const float* Wq    = (const float*)d_in[4];
    const float* bq    = (const float*)d_in[5];
    const float* Wk    = (const float*)d_in[6];
    const float* bk    = (const float*)d_in[7];
    const float* Wv    = (const float*)d_in[8];
    const float* bv    = (const float*)d_in[9];
    const float* Wo    = (const float*)d_in[10];
    const float* bo    = (const float*)d_in[11];
    const float* ln1w  = (const float*)d_in[12];
    const float* ln1b  = (const float*)d_in[13];
    const float* ln2w  = (const float*)d_in[14];
    const float* ln2b  = (const float*)d_in[15];
    const float* mw1   = (const float*)d_in[16];
    const float* mb1   = (const float*)d_in[17];
    const float* mw2   = (const float*)d_in[18];
    const float* mb2   = (const float*)d_in[19];
    const float* lnfw  = (const float*)d_in[20];
    const float* lnfb  = (const float*)d_in[21];
    const float* ow1   = (const float*)d_in[22];
    const float* ob1   = (const float*)d_in[23];
    const float* ow2   = (const float*)d_in[24];
    const float* ob2   = (const float*)d_in[25];

    const int M = N_TOK;
    char* ws = (char*)d_ws;

    // Workspace layout (byte offsets in MB):
    // [0,16)  x fp32          [16,24) xb bf16       [24,40) qkb / resid / cnnb
    // [40,48) vt bf16         [48,56) ab bf16       [40,64) hb bf16 (aliases vt+ab)
    // [64,~71) converted weights + bqkv
    float*  x     = (float*)(ws + 0);
    ushort* xb    = (ushort*)(ws + 16 * MB);
    ushort* qkb   = (ushort*)(ws + 24 * MB);
    float*  resid = (float*)(ws + 24 * MB);
    ushort* cnnb  = (ushort*)(ws + 24 * MB);
    ushort* vt    = (ushort*)(ws + 40 * MB);
    ushort* ab_   = (ushort*)(ws + 48 * MB);
    ushort* hb_   = (ushort*)(ws + 40 * MB);
    ushort* wb    = (ushort*)(ws + 64 * MB);

    ushort* cnn_wb = wb;                    // 131072
    ushort* Wob    = wb + 131072;           // 262144
    ushort* wqkv   = wb + 393216;           // 786432 = [L][768][256]
    ushort* mw1b   = wb + 1179648;          // 786432
    ushort* mw2b   = wb + 1966080;          // 786432
    ushort* ow1b   = wb + 2752512;          // 131072
    ushort* ow2b   = wb + 2883584;          // 262144
    float*  bqkv   = (float*)(ws + 64 * MB + 6291456);   // [L][768] fp32

    // conversions
    cvt_kernel<<<dim3(4096), dim3(256), 0, stream>>>(cnn, cnnb);
    cvt_kernel<<<dim3(64),  dim3(256), 0, stream>>>(cnn_w, cnn_wb);
    cvt_kernel<<<dim3(128), dim3(256), 0, stream>>>(Wo, Wob);
    cvt_kernel<<<dim3(384), dim3(256), 0, stream>>>(mw1, mw1b);
    cvt_kernel<<<dim3(384), dim3(256), 0, stream>>>(mw2, mw2b);
    cvt_kernel<<<dim3(64),  dim3(256), 0, stream>>>(ow1, ow1b);
    cvt_kernel<<<dim3(128), dim3(256), 0, stream>>>(ow2, ow2b);
    for (int i = 0; i < L_SZ; ++i) {
        cvt_kernel<<<dim3(32), dim3(256), 0, stream>>>(Wq + (size_t)i * 65536, wqkv + (size_t)i * 196608);
        cvt_kernel<<<dim3(32), dim3(256), 0, stream>>>(Wk + (size_t)i * 65536, wqkv + (size_t)i * 196608 + 65536);
        cvt_kernel<<<dim3(32), dim3(256), 0, stream>>>(Wv + (size_t)i * 65536, wqkv + (size_t)i * 196608 + 131072);
    }
    bqkv_kernel<<<dim3(12), dim3(256), 0, stream>>>(bq, bk, bv, bqkv);

    // x = cnn @ cnn_w^T + cnn_b + tok[0]  -> x fp32 + xb bf16
    gemm_bf16_kernel<0, 0, true, true><<<dim3(M / 128, E_SZ / 64), dim3(256), 0, stream>>>(
        cnnb, cnn_wb, cnn_b, tok, x, xb, nullptr, M, C_SZ, E_SZ);

    for (int i = 0; i < L_SZ; ++i) {
        // fused QKV: q|k -> qkb [N][512], v -> vt transposed [b][h][32][512]
        gemm_bf16_kernel<0, 1, false, false><<<dim3(M / 128, HID / 64), dim3(256), 0, stream>>>(
            xb, wqkv + (size_t)i * 196608, bqkv + (size_t)i * 768, nullptr,
            nullptr, qkb, vt, M, E_SZ, HID);

        attn_v3<<<dim3(B_SZ * H_SZ, S_SZ / 64), dim3(256), 0, stream>>>(qkb, vt, ab_);

        // attn_out = ab @ Wo^T + bo -> resid fp32
        gemm_bf16_kernel<0, 0, true, false><<<dim3(M / 128, E_SZ / 64), dim3(256), 0, stream>>>(
            ab_, Wob + (size_t)i * 65536, bo + (size_t)i * E_SZ, nullptr,
            resid, nullptr, nullptr, M, E_SZ, E_SZ);
        add_ln2_kernel<<<dim3(M / 4), dim3(256), 0, stream>>>(
            x, resid, ln1w + (size_t)i * E_SZ, ln1b + (size_t)i * E_SZ, xb);

        gemm_bf16_kernel<1, 0, false, true><<<dim3(M / 128, HID / 64), dim3(256), 0, stream>>>(
            xb, mw1b + (size_t)i * HID * E_SZ, mb1 + (size_t)i * HID, nullptr,
            nullptr, hb_, nullptr, M, E_SZ, HID);
        gemm_bf16_kernel<0, 0, true, false><<<dim3(M / 128, E_SZ / 64), dim3(256), 0, stream>>>(
            hb_, mw2b + (size_t)i * E_SZ * HID, mb2 + (size_t)i * E_SZ, nullptr,
            resid, nullptr, nullptr, M, HID, E_SZ);
        add_ln2_kernel<<<dim3(M / 4), dim3(256), 0, stream>>>(
            x, resid, ln2w + (size_t)i * E_SZ, ln2b + (size_t)i * E_SZ, xb);
    }

    // final LN -> xb
    add_ln2_kernel<<<dim3(M / 4), dim3(256), 0, stream>>>(x, nullptr, lnfw, lnfb, xb);

    // h = gelu(xb @ ow1^T + ob1) -> hb_ [N,512]
    gemm_bf16_kernel<1, 0, false, true><<<dim3(M / 128, (2 * E_SZ) / 64), dim3(256), 0, stream>>>(
        xb, ow1b, ob1, nullptr, nullptr, hb_, nullptr, M, E_SZ, 2 * E_SZ);
    // out = relu(hb @ ow2^T + ob2) -> d_out fp32
    gemm_bf16_kernel<2, 0, true, false><<<dim3(M / 128, C_SZ / 64), dim3(256), 0, stream>>>(
        hb_, ow2b, ob2, nullptr, (float*)d_out, nullptr, nullptr, M, 2 * E_SZ, C_SZ);
}